// Round 12
// baseline (535.598 us; speedup 1.0000x reference)
//
#include <hip/hip_runtime.h>

typedef _Float16 f16_t;
typedef f16_t f16x4 __attribute__((ext_vector_type(4)));
typedef f16_t f16x8 __attribute__((ext_vector_type(8)));
typedef float f32x4 __attribute__((ext_vector_type(4)));
typedef float f32x16 __attribute__((ext_vector_type(16)));

// 16x16x32: A[row=l&15][k=(l>>4)*8+j] / B[k][col=l&15]; D: row=(l>>4)*4+r, col=l&15
// 32x32x16: A[row=l&31][k=(l>>5)*8+j] / B[k][col=l&31]; D: col=l&31,
//           row=(r&3)+8*(r>>2)+4*(l>>5), r<16   [HW-verified m74/m101]
// Frag dual-use: a frag storing M[k][x] at lane=(x)+G*((k-half)), j=k&7 serves as
// A (row=x) and B (col=x) identically. k lane-maps cancel between A and B.
#define MFMA16(a,b,c) __builtin_amdgcn_mfma_f32_16x16x32_f16((a),(b),(c),0,0,0)
#define MFMA32(a,b,c) __builtin_amdgcn_mfma_f32_32x32x16_f16((a),(b),(c),0,0,0)

// bf16 round (RNE) — matches reference input rounding; exact in f16.
__device__ __forceinline__ float bfr(float x) { return (float)(__bf16)x; }

#define ACC16_ZERO {0.f,0.f,0.f,0.f,0.f,0.f,0.f,0.f,0.f,0.f,0.f,0.f,0.f,0.f,0.f,0.f}

// ---------------------------------------------------------------------------
// Pack weights, bf16-rounded. ew0/ew1/nw0/nw1 in 32-col frag format
// (frag(ks,nt): W[ks*16+(l>>5)*8+j][nt*32+(l&31)]), ew2/eLin/nw2/nLin in
// 16-col format (W[ks*32+(l>>4)*8+j][nt*16+(l&15)]). Same sizes/offsets.
// ---------------------------------------------------------------------------
__global__ void pack_weights_kernel(
    const float* __restrict__ ew0, const float* __restrict__ ew1,
    const float* __restrict__ ew2, const float* __restrict__ eL,
    const float* __restrict__ nw0, const float* __restrict__ nw1,
    const float* __restrict__ nw2, const float* __restrict__ nL,
    f16_t* __restrict__ dst)
{
    int tid = blockIdx.x * 256 + threadIdx.x;
    int fid = tid >> 6, lane = tid & 63;
    const float* src; int Ncols, foff, doff, fmt32;
    if (fid < 192)      { src = ew0; Ncols = 256; foff = 0;   doff = 0;      fmt32 = 1; }
    else if (fid < 320) { src = ew1; Ncols = 256; foff = 192; doff = 98304;  fmt32 = 1; }
    else if (fid < 384) { src = ew2; Ncols = 128; foff = 320; doff = 163840; fmt32 = 0; }
    else if (fid < 416) { src = eL;  Ncols = 128; foff = 384; doff = 196608; fmt32 = 0; }
    else if (fid < 544) { src = nw0; Ncols = 256; foff = 416; doff = 212992; fmt32 = 1; }
    else if (fid < 672) { src = nw1; Ncols = 256; foff = 544; doff = 278528; fmt32 = 1; }
    else if (fid < 736) { src = nw2; Ncols = 128; foff = 672; doff = 344064; fmt32 = 0; }
    else                { src = nL;  Ncols = 128; foff = 736; doff = 376832; fmt32 = 0; }
    int f = fid - foff;
    int col, kbase;
    if (fmt32) {
        int NT = Ncols >> 5;
        int ks = f / NT, nt = f - ks * NT;
        col = nt * 32 + (lane & 31);
        kbase = ks * 16 + ((lane >> 5) << 3);
    } else {
        int NT = Ncols >> 4;
        int ks = f / NT, nt = f - ks * NT;
        col = nt * 16 + (lane & 15);
        kbase = ks * 32 + ((lane >> 4) << 3);
    }
    f16x8 out;
    #pragma unroll
    for (int j = 0; j < 8; ++j)
        out[j] = (f16_t)bfr(src[(size_t)(kbase + j) * Ncols + col]);
    *reinterpret_cast<f16x8*>(dst + (size_t)doff + ((size_t)f * 64 + lane) * 8) = out;
}

// ---------------------------------------------------------------------------
// Pre-round LN gains/biases + layer biases to bf16 grid (f32 storage).
// pp: 0 elng(384) | 384 elnb | 768 eb0 | 1024 eb1 | 1280 eb2 | 1408 nlng
//     | 1664 nlnb | 1920 nb0 | 2176 nb1 | 2432 nb2  -> 2560 floats
// ---------------------------------------------------------------------------
__global__ void pack_params_kernel(
    const float* __restrict__ elng, const float* __restrict__ elnb,
    const float* __restrict__ eb0,  const float* __restrict__ eb1,
    const float* __restrict__ eb2,  const float* __restrict__ nlng,
    const float* __restrict__ nlnb, const float* __restrict__ nb0,
    const float* __restrict__ nb1,  const float* __restrict__ nb2,
    float* __restrict__ pp)
{
    int tid = blockIdx.x * 256 + threadIdx.x;
    if (tid >= 2560) return;
    const float* src; int off;
    if (tid < 384)       { src = elng; off = 0; }
    else if (tid < 768)  { src = elnb; off = 384; }
    else if (tid < 1024) { src = eb0;  off = 768; }
    else if (tid < 1280) { src = eb1;  off = 1024; }
    else if (tid < 1408) { src = eb2;  off = 1280; }
    else if (tid < 1664) { src = nlng; off = 1408; }
    else if (tid < 1920) { src = nlnb; off = 1664; }
    else if (tid < 2176) { src = nb0;  off = 1920; }
    else if (tid < 2432) { src = nb1;  off = 2176; }
    else                 { src = nb2;  off = 2432; }
    pp[tid] = bfr(src[tid - off]);
}

// ---------------------------------------------------------------------------
// Edge kernel: 64 edges/block, 1024 threads (16 waves), 2 blocks/CU.
// L1/L2 use 32x32x16 MFMA (swapped) on 32-fmt frags: 1 LDS read -> 32 KFLOP.
// L3 stays 16x16x32 un-swapped (coalesced out_e + 64B-grouped atomics).
// Phase0 thread map: all 16 k-slots of an edge within one wave -> shfl stats,
// no stats LDS, 5 barriers total.
// ---------------------------------------------------------------------------
__launch_bounds__(1024, 8)
__global__ void edge_kernel(
    const float* __restrict__ vfeat, const float* __restrict__ efeat,
    const int* __restrict__ eidx,
    const float* __restrict__ pp,          // pre-rounded params (edge @0..1407)
    const f16_t* __restrict__ pw,
    float* __restrict__ out_e, float* __restrict__ aggr, float* __restrict__ cnts,
    int Ee)
{
    __shared__ f16_t XF[48 * 512];   // 48KB: X 32fmt [ks<24][et<2]; h1 32fmt [0..31]; h2 16fmt [0..31]
    __shared__ f16_t ERF[16 * 512];  // 16KB: raw bf16 e, 16fmt [ks<4][et<4]
    __shared__ int cidx[64];

    const int t    = threadIdx.x;
    const int lane = t & 63;
    const int wv   = t >> 6;             // 0..15
    const size_t ebase = (size_t)blockIdx.x * 64;

    // ---- phase 0: gather + bf16-round -> regs; raw-e -> ERF (16fmt); shfl stats
    const int edge = t >> 4;             // 0..63
    const int slot = t & 15;             // k-octet index (k = i*128 + slot*8)
    const size_t eg0 = ebase + edge;
    const int r0 = eidx[eg0];
    const int c0 = eidx[(size_t)Ee + eg0];

    f16x8 oct[3];
    float s = 0.f, sq = 0.f;
    {
        const float4* e4 = (const float4*)efeat;
        const float4* v4 = (const float4*)vfeat;
        const float4* srcs[3];
        srcs[0] = &e4[eg0 * 32 + slot * 2];
        srcs[1] = &v4[(size_t)r0 * 32 + slot * 2];
        srcs[2] = &v4[(size_t)c0 * 32 + slot * 2];
        #pragma unroll
        for (int i = 0; i < 3; ++i) {
            float4 f0 = srcs[i][0];
            float4 f1 = srcs[i][1];
            float x0 = bfr(f0.x), x1 = bfr(f0.y), x2 = bfr(f0.z), x3 = bfr(f0.w);
            float x4 = bfr(f1.x), x5 = bfr(f1.y), x6 = bfr(f1.z), x7 = bfr(f1.w);
            s  += x0 + x1 + x2 + x3 + x4 + x5 + x6 + x7;
            sq += x0*x0 + x1*x1 + x2*x2 + x3*x3 + x4*x4 + x5*x5 + x6*x6 + x7*x7;
            f16x8 h;
            h[0] = (f16_t)x0; h[1] = (f16_t)x1; h[2] = (f16_t)x2; h[3] = (f16_t)x3;
            h[4] = (f16_t)x4; h[5] = (f16_t)x5; h[6] = (f16_t)x6; h[7] = (f16_t)x7;
            oct[i] = h;
        }
        // raw e (k<128) -> ERF 16fmt: frag=(k>>5)*4+(edge>>4), lane16=(edge&15)+16*((k&31)>>3)
        int fe = (slot >> 2) * 4 + (edge >> 4);
        int lane16 = (edge & 15) + 16 * (slot & 3);
        *reinterpret_cast<f16x8*>(&ERF[fe * 512 + lane16 * 8]) = oct[0];
        if (slot == 0) {
            cidx[edge] = c0;
            unsafeAtomicAdd(&cnts[c0], 1.0f);
        }
    }
    // all 16 slots of this edge live in one wave (lanes (edge&3)*16 + slot)
    s  += __shfl_xor(s, 1);  s  += __shfl_xor(s, 2);
    s  += __shfl_xor(s, 4);  s  += __shfl_xor(s, 8);
    sq += __shfl_xor(sq, 1); sq += __shfl_xor(sq, 2);
    sq += __shfl_xor(sq, 4); sq += __shfl_xor(sq, 8);
    const float mean = s * (1.f / 384.f);
    const float rstd = 1.f / sqrtf(sq * (1.f / 384.f) - mean * mean + 1e-5f);

    // ---- phase 1: LN in regs -> write X 32fmt frags
    {
        const float4* g4p = (const float4*)pp;            // elng
        const float4* bpp = (const float4*)(pp + 384);    // elnb
        const int et = edge >> 5;
        const int lane32 = (edge & 31) + 32 * (slot & 1); // (k>>3)&1 == slot&1
        #pragma unroll
        for (int i = 0; i < 3; ++i) {
            int q = (i * 16 + slot) * 2;
            float4 g0 = g4p[q], g1 = g4p[q + 1];
            float4 bb0 = bpp[q], bb1 = bpp[q + 1];
            f16x8 h = oct[i];
            f16x8 y;
            float tt, cc;
            tt = rstd * g0.x; cc = bb0.x - mean * tt; y[0] = (f16_t)((float)h[0] * tt + cc);
            tt = rstd * g0.y; cc = bb0.y - mean * tt; y[1] = (f16_t)((float)h[1] * tt + cc);
            tt = rstd * g0.z; cc = bb0.z - mean * tt; y[2] = (f16_t)((float)h[2] * tt + cc);
            tt = rstd * g0.w; cc = bb0.w - mean * tt; y[3] = (f16_t)((float)h[3] * tt + cc);
            tt = rstd * g1.x; cc = bb1.x - mean * tt; y[4] = (f16_t)((float)h[4] * tt + cc);
            tt = rstd * g1.y; cc = bb1.y - mean * tt; y[5] = (f16_t)((float)h[5] * tt + cc);
            tt = rstd * g1.z; cc = bb1.z - mean * tt; y[6] = (f16_t)((float)h[6] * tt + cc);
            tt = rstd * g1.w; cc = bb1.w - mean * tt; y[7] = (f16_t)((float)h[7] * tt + cc);
            int ks = i * 8 + (slot >> 1);                 // 0..23
            *reinterpret_cast<f16x8*>(&XF[(ks * 2 + et) * 512 + lane32 * 8]) = y;
        }
    }
    __syncthreads();

    const int el31 = lane & 31;
    const int h2b  = lane >> 5;

    // ---- layer 1 (32x32 swapped): h1 = relu(x @ ew0 + b0)
    // wave = colgroup c8 (wv&7, 32 cols) x rowhalf rh (wv>>3, 32 edges)
    {
        const int c8 = wv & 7, rh = wv >> 3;
        f32x16 acc = ACC16_ZERO;
        const f16_t* bw = pw;                       // ew0 32fmt (NT=8)
        #pragma unroll
        for (int ks = 0; ks < 24; ++ks) {
            f16x8 wa = *reinterpret_cast<const f16x8*>(
                &bw[((size_t)(ks * 8 + c8) * 64 + lane) * 8]);
            f16x8 xb = *reinterpret_cast<const f16x8*>(
                &XF[(ks * 2 + rh) * 512 + lane * 8]);
            acc = MFMA32(wa, xb, acc);
        }
        __syncthreads();   // all X reads done before overwriting frags 0..31
        #pragma unroll
        for (int c = 0; c < 4; ++c) {
            int oc0 = c8 * 32 + 8 * c + 4 * h2b;    // 4 consecutive outcols
            float4 bs = *reinterpret_cast<const float4*>(&pp[768 + oc0]);  // eb0
            f16x4 hv;
            hv[0] = (f16_t)fmaxf(acc[4*c+0] + bs.x, 0.f);
            hv[1] = (f16_t)fmaxf(acc[4*c+1] + bs.y, 0.f);
            hv[2] = (f16_t)fmaxf(acc[4*c+2] + bs.z, 0.f);
            hv[3] = (f16_t)fmaxf(acc[4*c+3] + bs.w, 0.f);
            int frag = (c8 * 2 + (c >> 1)) * 2 + rh;    // h1 32fmt [ks<16][et=rh]
            *reinterpret_cast<f16x4*>(
                &XF[frag * 512 + (el31 + 32 * (c & 1)) * 8 + 4 * h2b]) = hv;
        }
    }
    __syncthreads();

    // ---- layer 2 (32x32 swapped): h2 = relu(h1 @ ew1 + b1) -> 16fmt frags
    {
        const int c8 = wv & 7, rh = wv >> 3;
        f32x16 acc = ACC16_ZERO;
        const f16_t* bw = pw + 98304;               // ew1 32fmt (NT=8)
        #pragma unroll
        for (int ks = 0; ks < 16; ++ks) {
            f16x8 wa = *reinterpret_cast<const f16x8*>(
                &bw[((size_t)(ks * 8 + c8) * 64 + lane) * 8]);
            f16x8 xb = *reinterpret_cast<const f16x8*>(
                &XF[(ks * 2 + rh) * 512 + lane * 8]);
            acc = MFMA32(wa, xb, acc);
        }
        __syncthreads();   // all h1 reads done before overwrite
        const int eg16 = rh * 32 + el31;            // global edge in block
        #pragma unroll
        for (int c = 0; c < 4; ++c) {
            int oc0 = c8 * 32 + 8 * c + 4 * h2b;
            float4 bs = *reinterpret_cast<const float4*>(&pp[1024 + oc0]); // eb1
            f16x4 hv;
            hv[0] = (f16_t)fmaxf(acc[4*c+0] + bs.x, 0.f);
            hv[1] = (f16_t)fmaxf(acc[4*c+1] + bs.y, 0.f);
            hv[2] = (f16_t)fmaxf(acc[4*c+2] + bs.z, 0.f);
            hv[3] = (f16_t)fmaxf(acc[4*c+3] + bs.w, 0.f);
            // h2 16fmt: frag = (oc>>5)*4 + (edge>>4) = c8*4 + (eg16>>4)
            int frag = c8 * 4 + (eg16 >> 4);
            *reinterpret_cast<f16x4*>(
                &XF[frag * 512 + ((eg16 & 15) + 16 * c) * 8 + 4 * h2b]) = hv;
        }
    }
    __syncthreads();

    // ---- layer 3 + residual (16x16 UN-swapped): relu(h2 @ ew2 + b2) + e @ eLin
    // wave: cols [cw*16,+16), edge tiles {rw*2, rw*2+1}
    {
        const int cw = wv & 7;
        const int rw = wv >> 3;
        const int r16 = lane & 15;
        const int g4i = lane >> 4;
        f32x4 accF[2] = {}, accR[2] = {};
        const f16_t* bw = pw + 163840;              // ew2 16fmt (NT=8)
        #pragma unroll
        for (int ks = 0; ks < 8; ++ks) {
            f16x8 wb = *reinterpret_cast<const f16x8*>(
                &bw[((size_t)(ks * 8 + cw) * 64 + lane) * 8]);
            #pragma unroll
            for (int e2 = 0; e2 < 2; ++e2) {
                f16x8 xa = *reinterpret_cast<const f16x8*>(
                    &XF[(ks * 4 + rw * 2 + e2) * 512 + lane * 8]);
                accF[e2] = MFMA16(xa, wb, accF[e2]);
            }
        }
        const f16_t* bwL = pw + 196608;             // eLin 16fmt (NT=8)
        #pragma unroll
        for (int ks = 0; ks < 4; ++ks) {
            f16x8 wb = *reinterpret_cast<const f16x8*>(
                &bwL[((size_t)(ks * 8 + cw) * 64 + lane) * 8]);
            #pragma unroll
            for (int e2 = 0; e2 < 2; ++e2) {
                f16x8 ea = *reinterpret_cast<const f16x8*>(
                    &ERF[(ks * 4 + rw * 2 + e2) * 512 + lane * 8]);
                accR[e2] = MFMA16(ea, wb, accR[e2]);
            }
        }
        int c = cw * 16 + r16;
        float bias = pp[1280 + c];                  // eb2
        #pragma unroll
        for (int e2 = 0; e2 < 2; ++e2)
            #pragma unroll
            for (int qi = 0; qi < 4; ++qi) {
                int rr = (rw * 2 + e2) * 16 + g4i * 4 + qi;
                float val = accR[e2][qi] + fmaxf(accF[e2][qi] + bias, 0.f);
                size_t eg2 = ebase + rr;
                out_e[eg2 * 128 + c] = val;
                unsafeAtomicAdd(&aggr[(size_t)cidx[rr] * 128 + c], val);
            }
    }
}

// ---------------------------------------------------------------------------
// Node kernel: 32 nodes/block, 512 threads (8 waves), 4 blocks/CU (33KB LDS).
// L1/L2 32x32 swapped (8 waves = 8 colgroups, no duplication); L3 16x16.
// ---------------------------------------------------------------------------
__launch_bounds__(512, 6)
__global__ void node_kernel(
    const float* __restrict__ vfeat, const float* __restrict__ aggr,
    const float* __restrict__ cnts,
    const float* __restrict__ pp,                   // params (node @1408..2559)
    const f16_t* __restrict__ pw,                   // node weight base (nw0)
    float* __restrict__ out_v, int Nn)
{
    __shared__ f16_t XF[16 * 512];   // 16KB: X 32fmt [ks<16]; reused h2 16fmt [ks<8][et<2]
    __shared__ f16_t H1[16 * 512];   // 16KB: h1 32fmt [ks<16]

    const int t    = threadIdx.x;
    const int lane = t & 63;
    const int wv   = t >> 6;           // 0..7
    const size_t nbase = (size_t)blockIdx.x * 32;

    // ---- phase 0
    const int nl   = t >> 4;           // 0..31
    const int slot = t & 15;
    const size_t ng = nbase + nl;
    const bool valid = ng < (size_t)Nn;

    f16x8 oct[2];
    float s = 0.f, sq = 0.f;
    {
        float inv = 1.f;
        if (valid) inv = 1.f / fmaxf(cnts[ng], 1.f);
        const float4* a4 = (const float4*)aggr;
        const float4* v4 = (const float4*)vfeat;
        #pragma unroll
        for (int i = 0; i < 2; ++i) {
            float x0=0.f,x1=0.f,x2=0.f,x3=0.f,x4=0.f,x5=0.f,x6=0.f,x7=0.f;
            if (valid) {
                const float4* srcp = (i == 0) ? &a4[ng * 32 + slot * 2]
                                              : &v4[ng * 32 + slot * 2];
                float4 f0 = srcp[0], f1 = srcp[1];
                if (i == 0) {        // aggr/cnt: derived f32, not rounded
                    x0 = f0.x*inv; x1 = f0.y*inv; x2 = f0.z*inv; x3 = f0.w*inv;
                    x4 = f1.x*inv; x5 = f1.y*inv; x6 = f1.z*inv; x7 = f1.w*inv;
                } else {             // v: bf16-rounded
                    x0 = bfr(f0.x); x1 = bfr(f0.y); x2 = bfr(f0.z); x3 = bfr(f0.w);
                    x4 = bfr(f1.x); x5 = bfr(f1.y); x6 = bfr(f1.z); x7 = bfr(f1.w);
                }
            }
            s  += x0 + x1 + x2 + x3 + x4 + x5 + x6 + x7;
            sq += x0*x0 + x1*x1 + x2*x2 + x3*x3 + x4*x4 + x5*x5 + x6*x6 + x7*x7;
            f16x8 h;
            h[0] = (f16_t)x0; h[1] = (f16_t)x1; h[2] = (f16_t)x2; h[3] = (f16_t)x3;
            h[4] = (f16_t)x4; h[5] = (f16_t)x5; h[6] = (f16_t)x6; h[7] = (f16_t)x7;
            oct[i] = h;
        }
    }
    s  += __shfl_xor(s, 1);  s  += __shfl_xor(s, 2);
    s  += __shfl_xor(s, 4);  s  += __shfl_xor(s, 8);
    sq += __shfl_xor(sq, 1); sq += __shfl_xor(sq, 2);
    sq += __shfl_xor(sq, 4); sq += __shfl_xor(sq, 8);
    const float mean = s * (1.f / 256.f);
    const float rstd = 1.f / sqrtf(sq * (1.f / 256.f) - mean * mean + 1e-5f);

    // ---- phase 1: LN -> X 32fmt frags [ks<16]
    {
        const float4* g4p = (const float4*)(pp + 1408);   // nlng
        const float4* bpp = (const float4*)(pp + 1664);   // nlnb
        const int lane32 = nl + 32 * (slot & 1);
        #pragma unroll
        for (int i = 0; i < 2; ++i) {
            int q = (i * 16 + slot) * 2;
            float4 g0 = g4p[q], g1 = g4p[q + 1];
            float4 bb0 = bpp[q], bb1 = bpp[q + 1];
            f16x8 h = oct[i];
            f16x8 y;
            float tt, cc;
            tt = rstd * g0.x; cc = bb0.x - mean * tt; y[0] = (f16_t)((float)h[0] * tt + cc);
            tt = rstd * g0.y; cc = bb0.y - mean * tt; y[1] = (f16_t)((float)h[1] * tt + cc);
            tt = rstd * g0.z; cc = bb0.z - mean * tt; y[2] = (f16_t)((float)h[2] * tt + cc);
            tt = rstd * g0.w; cc = bb0.w - mean * tt; y[3] = (f16_t)((float)h[3] * tt + cc);
            tt = rstd * g1.x; cc = bb1.x - mean * tt; y[4] = (f16_t)((float)h[4] * tt + cc);
            tt = rstd * g1.y; cc = bb1.y - mean * tt; y[5] = (f16_t)((float)h[5] * tt + cc);
            tt = rstd * g1.z; cc = bb1.z - mean * tt; y[6] = (f16_t)((float)h[6] * tt + cc);
            tt = rstd * g1.w; cc = bb1.w - mean * tt; y[7] = (f16_t)((float)h[7] * tt + cc);
            int ks = i * 8 + (slot >> 1);                 // 0..15
            *reinterpret_cast<f16x8*>(&XF[ks * 512 + lane32 * 8]) = y;
        }
    }
    __syncthreads();

    const int n31 = lane & 31;
    const int h2b = lane >> 5;

    // ---- layer 1 (32x32 swapped): wave = colgroup wv (32 cols), all 32 nodes
    {
        f32x16 acc = ACC16_ZERO;
        const f16_t* bw = pw;                       // nw0 32fmt (NT=8)
        #pragma unroll
        for (int ks = 0; ks < 16; ++ks) {
            f16x8 wa = *reinterpret_cast<const f16x8*>(
                &bw[((size_t)(ks * 8 + wv) * 64 + lane) * 8]);
            f16x8 xb = *reinterpret_cast<const f16x8*>(&XF[ks * 512 + lane * 8]);
            acc = MFMA32(wa, xb, acc);
        }
        // writes go to H1 (disjoint region) — no barrier needed before them
        #pragma unroll
        for (int c = 0; c < 4; ++c) {
            int oc0 = wv * 32 + 8 * c + 4 * h2b;
            float4 bs = *reinterpret_cast<const float4*>(&pp[1920 + oc0]);  // nb0
            f16x4 hv;
            hv[0] = (f16_t)fmaxf(acc[4*c+0] + bs.x, 0.f);
            hv[1] = (f16_t)fmaxf(acc[4*c+1] + bs.y, 0.f);
            hv[2] = (f16_t)fmaxf(acc[4*c+2] + bs.z, 0.f);
            hv[3] = (f16_t)fmaxf(acc[4*c+3] + bs.w, 0.f);
            int frag = wv * 2 + (c >> 1);               // h1 32fmt [ks<16]
            *reinterpret_cast<f16x4*>(
                &H1[frag * 512 + (n31 + 32 * (c & 1)) * 8 + 4 * h2b]) = hv;
        }
    }
    __syncthreads();

    // ---- layer 2 (32x32 swapped): h2 = relu(h1 @ nw1 + b1) -> 16fmt into XF
    {
        f32x16 acc = ACC16_ZERO;
        const f16_t* bw = pw + 65536;               // nw1 32fmt (NT=8)
        #pragma unroll
        for (int ks = 0; ks < 16; ++ks) {
            f16x8 wa = *reinterpret_cast<const f16x8*>(
                &bw[((size_t)(ks * 8 + wv) * 64 + lane) * 8]);
            f16x8 xb = *reinterpret_cast<const f16x8*>(&H1[ks * 512 + lane * 8]);
            acc = MFMA32(wa, xb, acc);
        }
        // XF reads all finished before the post-L1 barrier — safe to overwrite
        #pragma unroll
        for (int c = 0; c < 4; ++c) {
            int oc0 = wv * 32 + 8 * c + 4 * h2b;
            float4 bs = *reinterpret_cast<const float4*>(&pp[2176 + oc0]);  // nb1
            f16x4 hv;
            hv[0] = (f16_t)fmaxf(acc[4*c+0] + bs.x, 0.f);
            hv[1] = (f16_t)fmaxf(acc[4*c+1] + bs.y, 0.f);
            hv[2] = (f16_t)fmaxf(acc[4*c+2] + bs.z, 0.f);
            hv[3] = (f16_t)fmaxf(acc[4*c+3] + bs.w, 0.f);
            // h2 16fmt: frag = (oc>>5)*2 + (node>>4) = wv*2 + (n31>>4)
            int frag = wv * 2 + (n31 >> 4);
            *reinterpret_cast<f16x4*>(
                &XF[frag * 512 + ((n31 & 15) + 16 * c) * 8 + 4 * h2b]) = hv;
        }
    }
    __syncthreads();

    // ---- layer 3 + residual (16x16 UN-swapped): wave owns cols [wv*16,+16)
    {
        const int r16 = lane & 15;
        const int g4i = lane >> 4;
        f32x4 accF[2] = {}, accR[2] = {};
        const f16_t* bw = pw + 131072;              // nw2 16fmt (NT=8)
        #pragma unroll
        for (int ks = 0; ks < 8; ++ks) {
            f16x8 wb = *reinterpret_cast<const f16x8*>(
                &bw[((size_t)(ks * 8 + wv) * 64 + lane) * 8]);
            #pragma unroll
            for (int nt = 0; nt < 2; ++nt) {
                f16x8 xa = *reinterpret_cast<const f16x8*>(
                    &XF[(ks * 2 + nt) * 512 + lane * 8]);
                accF[nt] = MFMA16(xa, wb, accF[nt]);
            }
        }
        const f16_t* bwL = pw + 163840;             // nLin 16fmt (NT=8)
        #pragma unroll
        for (int ks = 0; ks < 4; ++ks) {
            f16x8 wb = *reinterpret_cast<const f16x8*>(
                &bwL[((size_t)(ks * 8 + wv) * 64 + lane) * 8]);
            #pragma unroll
            for (int nt = 0; nt < 2; ++nt) {
                size_t rv = nbase + (size_t)(nt * 16 + r16);
                if (rv >= (size_t)Nn) rv = (size_t)Nn - 1;
                const float4* src = (const float4*)&vfeat[rv * 128 + ks * 32 + g4i * 8];
                float4 f0 = src[0];
                float4 f1 = src[1];
                f16x8 va;
                va[0] = (f16_t)bfr(f0.x); va[1] = (f16_t)bfr(f0.y);
                va[2] = (f16_t)bfr(f0.z); va[3] = (f16_t)bfr(f0.w);
                va[4] = (f16_t)bfr(f1.x); va[5] = (f16_t)bfr(f1.y);
                va[6] = (f16_t)bfr(f1.z); va[7] = (f16_t)bfr(f1.w);
                accR[nt] = MFMA16(va, wb, accR[nt]);
            }
        }
        int c = wv * 16 + r16;
        float bias = pp[2432 + c];                  // nb2
        #pragma unroll
        for (int nt = 0; nt < 2; ++nt)
            #pragma unroll
            for (int qi = 0; qi < 4; ++qi) {
                int rr = nt * 16 + g4i * 4 + qi;
                size_t ng2 = nbase + rr;
                if (ng2 < (size_t)Nn) {
                    float val = accR[nt][qi] + fmaxf(accF[nt][qi] + bias, 0.f);
                    out_v[ng2 * 128 + c] = val;
                }
            }
    }
}

// ---------------------------------------------------------------------------
extern "C" void kernel_launch(void* const* d_in, const int* in_sizes, int n_in,
                              void* d_out, int out_size, void* d_ws, size_t ws_size,
                              hipStream_t stream)
{
    const float* v    = (const float*)d_in[0];
    const float* e    = (const float*)d_in[1];
    const int*   eidx = (const int*)d_in[2];
    const float* elng = (const float*)d_in[3];
    const float* elnb = (const float*)d_in[4];
    const float* ew0  = (const float*)d_in[5];
    const float* eb0  = (const float*)d_in[6];
    const float* ew1  = (const float*)d_in[7];
    const float* eb1  = (const float*)d_in[8];
    const float* ew2  = (const float*)d_in[9];
    const float* eb2  = (const float*)d_in[10];
    const float* eLin = (const float*)d_in[11];
    const float* nlng = (const float*)d_in[12];
    const float* nlnb = (const float*)d_in[13];
    const float* nw0  = (const float*)d_in[14];
    const float* nb0  = (const float*)d_in[15];
    const float* nw1  = (const float*)d_in[16];
    const float* nb1  = (const float*)d_in[17];
    const float* nw2  = (const float*)d_in[18];
    const float* nb2  = (const float*)d_in[19];
    const float* nLin = (const float*)d_in[20];

    const int Nn = in_sizes[0] / 128;
    const int Ee = in_sizes[1] / 128;

    float* out_v = (float*)d_out;
    float* out_e = out_v + (size_t)Nn * 128;

    float* aggr = (float*)d_ws;                       // [Nn][128] f32
    float* cnts = aggr + (size_t)Nn * 128;            // [Nn] f32
    f16_t* packw = (f16_t*)((char*)d_ws + (size_t)Nn * 129 * 4);  // 393216 f16
    float* pp = (float*)((char*)packw + 393216 * 2);  // 2560 f32 params

    hipMemsetAsync(d_ws, 0, (size_t)Nn * 129 * 4, stream);

    pack_weights_kernel<<<192, 256, 0, stream>>>(ew0, ew1, ew2, eLin,
                                                 nw0, nw1, nw2, nLin, packw);
    pack_params_kernel<<<10, 256, 0, stream>>>(elng, elnb, eb0, eb1, eb2,
                                               nlng, nlnb, nb0, nb1, nb2, pp);

    edge_kernel<<<(Ee + 63) / 64, 1024, 0, stream>>>(v, e, eidx, pp, packw,
                                                     out_e, aggr, cnts, Ee);

    node_kernel<<<(Nn + 31) / 32, 512, 0, stream>>>(v, aggr, cnts, pp,
                                                    packw + 212992, out_v, Nn);
}

// Round 14
// 406.695 us; speedup vs baseline: 1.3170x; 1.3170x over previous
//
#include <hip/hip_runtime.h>

typedef _Float16 f16_t;
typedef f16_t f16x4 __attribute__((ext_vector_type(4)));
typedef f16_t f16x8 __attribute__((ext_vector_type(8)));
typedef float f32x4 __attribute__((ext_vector_type(4)));

// mfma_f32_16x16x32_f16 fragment mapping (A and B identical): lane l, elem j ->
//   A[row=l&15][k=(l>>4)*8+j] / B[k=(l>>4)*8+j][col=l&15]
// D: lane l -> D[row=(l>>4)*4+reg][col=l&15]
// A 1KB frag storing M[k][x] at lane=(x&15)+16*((k&31)>>3), j=k&7 serves as
// A-frag (row=x) and B-frag (col=x) identically.
#define MFMA16(a, b, c) __builtin_amdgcn_mfma_f32_16x16x32_f16((a), (b), (c), 0, 0, 0)

// bf16 round (RNE) — matches reference input rounding; exact in f16.
__device__ __forceinline__ float bfr(float x) { return (float)(__bf16)x; }

// ---------------------------------------------------------------------------
// Pack fp32 weights into f16 MFMA fragment order, bf16-rounded (16-col fmt).
// frag (kstep, ntile): lane l, elem j -> W[kstep*32+(l>>4)*8+j][ntile*16+(l&15)]
// ---------------------------------------------------------------------------
__global__ void pack_weights_kernel(
    const float* __restrict__ ew0, const float* __restrict__ ew1,
    const float* __restrict__ ew2, const float* __restrict__ eL,
    const float* __restrict__ nw0, const float* __restrict__ nw1,
    const float* __restrict__ nw2, const float* __restrict__ nL,
    f16_t* __restrict__ dst)
{
    int tid = blockIdx.x * 256 + threadIdx.x;
    int fid = tid >> 6, lane = tid & 63;
    const float* src; int Ncols, foff, doff;
    if (fid < 192)      { src = ew0; Ncols = 256; foff = 0;   doff = 0;      }
    else if (fid < 320) { src = ew1; Ncols = 256; foff = 192; doff = 98304;  }
    else if (fid < 384) { src = ew2; Ncols = 128; foff = 320; doff = 163840; }
    else if (fid < 416) { src = eL;  Ncols = 128; foff = 384; doff = 196608; }
    else if (fid < 544) { src = nw0; Ncols = 256; foff = 416; doff = 212992; }
    else if (fid < 672) { src = nw1; Ncols = 256; foff = 544; doff = 278528; }
    else if (fid < 736) { src = nw2; Ncols = 128; foff = 672; doff = 344064; }
    else                { src = nL;  Ncols = 128; foff = 736; doff = 376832; }
    int f = fid - foff;
    int NT = Ncols >> 4;
    int kstep = f / NT, ntile = f - kstep * NT;
    int col = ntile * 16 + (lane & 15);
    int kbase = kstep * 32 + ((lane >> 4) << 3);
    f16x8 out;
    #pragma unroll
    for (int j = 0; j < 8; ++j)
        out[j] = (f16_t)bfr(src[(size_t)(kbase + j) * Ncols + col]);
    *reinterpret_cast<f16x8*>(dst + (size_t)doff + ((size_t)f * 64 + lane) * 8) = out;
}

// ---------------------------------------------------------------------------
// Pre-round LN gains/biases + layer biases to bf16 grid (f32 storage).
// pp: 0 elng(384) | 384 elnb | 768 eb0 | 1024 eb1 | 1280 eb2 | 1408 nlng
//     | 1664 nlnb | 1920 nb0 | 2176 nb1 | 2432 nb2  -> 2560 floats
// ---------------------------------------------------------------------------
__global__ void pack_params_kernel(
    const float* __restrict__ elng, const float* __restrict__ elnb,
    const float* __restrict__ eb0,  const float* __restrict__ eb1,
    const float* __restrict__ eb2,  const float* __restrict__ nlng,
    const float* __restrict__ nlnb, const float* __restrict__ nb0,
    const float* __restrict__ nb1,  const float* __restrict__ nb2,
    float* __restrict__ pp)
{
    int tid = blockIdx.x * 256 + threadIdx.x;
    if (tid >= 2560) return;
    const float* src; int off;
    if (tid < 384)       { src = elng; off = 0; }
    else if (tid < 768)  { src = elnb; off = 384; }
    else if (tid < 1024) { src = eb0;  off = 768; }
    else if (tid < 1280) { src = eb1;  off = 1024; }
    else if (tid < 1408) { src = eb2;  off = 1280; }
    else if (tid < 1664) { src = nlng; off = 1408; }
    else if (tid < 1920) { src = nlnb; off = 1664; }
    else if (tid < 2176) { src = nb0;  off = 1920; }
    else if (tid < 2432) { src = nb1;  off = 2176; }
    else                 { src = nb2;  off = 2432; }
    pp[tid] = bfr(src[tid - off]);
}

// ---------------------------------------------------------------------------
// Edge kernel: 64 edges/block, 1024 threads (16 waves), 2 blocks/CU.
// R11 structure (conflict-free frag-linear LDS, 2-deep weight prefetch,
// pre-rounded params) + non-temporal out_e stores (no L2 allocation ->
// aggr atomic lines stay resident).
// ---------------------------------------------------------------------------
__launch_bounds__(1024, 8)
__global__ void edge_kernel(
    const float* __restrict__ vfeat, const float* __restrict__ efeat,
    const int* __restrict__ eidx,
    const float* __restrict__ pp,          // pre-rounded params (edge @0..1407)
    const f16_t* __restrict__ pw,
    float* __restrict__ out_e, float* __restrict__ aggr, float* __restrict__ cnts,
    int Ee)
{
    __shared__ f16_t XF[12 * 4 * 512];   // 48KB: X frags [ks<12][et<4]; reused h1/h2
    __shared__ f16_t ERF[4 * 4 * 512];   // 16KB: raw bf16 e frags
    __shared__ float SB[64 * 8];         // 2KB: per-edge partial stats
    __shared__ int cidx[64];

    const int t    = threadIdx.x;
    const int lane = t & 63;
    const int wv   = t >> 6;             // 0..15
    const int r16  = lane & 15;
    const int g4i  = lane >> 4;
    const size_t ebase = (size_t)blockIdx.x * 64;

    // ---- phase 0: transposed gather -> regs; raw-e -> ERF; partial LN stats
    const int et_  = wv >> 2;
    const int sq4  = wv & 3;
    const int edge = et_ * 16 + r16;
    const int slot = sq4 * 4 + g4i;      // slot&3 == g4i
    const size_t eg0 = ebase + edge;
    const int r0 = eidx[eg0];
    const int c0 = eidx[(size_t)Ee + eg0];

    f16x8 oct[3];
    float s = 0.f, sq = 0.f;
    {
        const float4* e4 = (const float4*)efeat;
        const float4* v4 = (const float4*)vfeat;
        const float4* srcs[3];
        srcs[0] = &e4[eg0 * 32 + slot * 2];
        srcs[1] = &v4[(size_t)r0 * 32 + slot * 2];
        srcs[2] = &v4[(size_t)c0 * 32 + slot * 2];
        #pragma unroll
        for (int i = 0; i < 3; ++i) {
            float4 f0 = srcs[i][0];
            float4 f1 = srcs[i][1];
            float x0 = bfr(f0.x), x1 = bfr(f0.y), x2 = bfr(f0.z), x3 = bfr(f0.w);
            float x4 = bfr(f1.x), x5 = bfr(f1.y), x6 = bfr(f1.z), x7 = bfr(f1.w);
            s  += x0 + x1 + x2 + x3 + x4 + x5 + x6 + x7;
            sq += x0*x0 + x1*x1 + x2*x2 + x3*x3 + x4*x4 + x5*x5 + x6*x6 + x7*x7;
            f16x8 h;
            h[0] = (f16_t)x0; h[1] = (f16_t)x1; h[2] = (f16_t)x2; h[3] = (f16_t)x3;
            h[4] = (f16_t)x4; h[5] = (f16_t)x5; h[6] = (f16_t)x6; h[7] = (f16_t)x7;
            oct[i] = h;
        }
        *reinterpret_cast<f16x8*>(&ERF[(sq4 * 4 + et_) * 512 + lane * 8]) = oct[0];
        if (slot == 0) {
            cidx[edge] = c0;
            unsafeAtomicAdd(&cnts[c0], 1.0f);
        }
    }
    s  += __shfl_xor(s, 16);  s  += __shfl_xor(s, 32);
    sq += __shfl_xor(sq, 16); sq += __shfl_xor(sq, 32);
    if (g4i == 0)
        *reinterpret_cast<float2*>(&SB[edge * 8 + sq4 * 2]) = make_float2(s, sq);
    __syncthreads();

    // ---- phase 1: totals -> LN (2-fma form) -> write X frags
    {
        float4 p0 = *reinterpret_cast<const float4*>(&SB[edge * 8]);
        float4 p1 = *reinterpret_cast<const float4*>(&SB[edge * 8 + 4]);
        float S = p0.x + p0.z + p1.x + p1.z;
        float Q = p0.y + p0.w + p1.y + p1.w;
        const float mean = S * (1.f / 384.f);
        const float rstd = 1.f / sqrtf(Q * (1.f / 384.f) - mean * mean + 1e-5f);
        const float4* g4p = (const float4*)pp;            // elng (pre-rounded)
        const float4* bpp = (const float4*)(pp + 384);    // elnb
        #pragma unroll
        for (int i = 0; i < 3; ++i) {
            int q = (i * 16 + slot) * 2;
            float4 g0 = g4p[q], g1 = g4p[q + 1];
            float4 bb0 = bpp[q], bb1 = bpp[q + 1];
            f16x8 h = oct[i];
            f16x8 y;
            float tt, cc;
            tt = rstd * g0.x; cc = bb0.x - mean * tt; y[0] = (f16_t)((float)h[0] * tt + cc);
            tt = rstd * g0.y; cc = bb0.y - mean * tt; y[1] = (f16_t)((float)h[1] * tt + cc);
            tt = rstd * g0.z; cc = bb0.z - mean * tt; y[2] = (f16_t)((float)h[2] * tt + cc);
            tt = rstd * g0.w; cc = bb0.w - mean * tt; y[3] = (f16_t)((float)h[3] * tt + cc);
            tt = rstd * g1.x; cc = bb1.x - mean * tt; y[4] = (f16_t)((float)h[4] * tt + cc);
            tt = rstd * g1.y; cc = bb1.y - mean * tt; y[5] = (f16_t)((float)h[5] * tt + cc);
            tt = rstd * g1.z; cc = bb1.z - mean * tt; y[6] = (f16_t)((float)h[6] * tt + cc);
            tt = rstd * g1.w; cc = bb1.w - mean * tt; y[7] = (f16_t)((float)h[7] * tt + cc);
            int ks = i * 4 + sq4;
            *reinterpret_cast<f16x8*>(&XF[(ks * 4 + et_) * 512 + lane * 8]) = y;
        }
    }
    __syncthreads();

    // ---- layer 1 (swapped, 2-deep weight prefetch): wave owns cols [wv*16,+16)
    {
        f32x4 acc[4] = {};
        const f16_t* bw = pw;                       // ew0 (NT=16)
        f16x8 wA = *reinterpret_cast<const f16x8*>(&bw[((size_t)(wv) * 64 + lane) * 8]);
        f16x8 wB = *reinterpret_cast<const f16x8*>(&bw[((size_t)(16 + wv) * 64 + lane) * 8]);
        #pragma unroll
        for (int ks = 0; ks < 12; ++ks) {
            f16x8 wN = wB;
            if (ks + 2 < 12)
                wN = *reinterpret_cast<const f16x8*>(
                    &bw[((size_t)((ks + 2) * 16 + wv) * 64 + lane) * 8]);
            #pragma unroll
            for (int et = 0; et < 4; ++et) {
                f16x8 xb = *reinterpret_cast<const f16x8*>(
                    &XF[(ks * 4 + et) * 512 + lane * 8]);
                acc[et] = MFMA16(wA, xb, acc[et]);
            }
            wA = wB; wB = wN;
        }
        __syncthreads();   // all X reads done before overwriting frags 0..7
        float4 bs = *reinterpret_cast<const float4*>(&pp[768 + wv * 16 + g4i * 4]); // eb0
        int ks2 = wv >> 1;
        int lane2 = r16 + 16 * ((wv & 1) * 2 + (g4i >> 1));
        int j0 = (g4i & 1) * 4;
        #pragma unroll
        for (int et = 0; et < 4; ++et) {
            f16x4 hv;
            hv[0] = (f16_t)fmaxf(acc[et][0] + bs.x, 0.f);
            hv[1] = (f16_t)fmaxf(acc[et][1] + bs.y, 0.f);
            hv[2] = (f16_t)fmaxf(acc[et][2] + bs.z, 0.f);
            hv[3] = (f16_t)fmaxf(acc[et][3] + bs.w, 0.f);
            *reinterpret_cast<f16x4*>(&XF[(ks2 * 4 + et) * 512 + lane2 * 8 + j0]) = hv;
        }
    }
    __syncthreads();

    // ---- layer 2 (swapped, prefetch): h2 = relu(h1 @ ew1 + b1)
    {
        f32x4 acc[4] = {};
        const f16_t* bw = pw + 98304;               // ew1 (NT=16)
        f16x8 wA = *reinterpret_cast<const f16x8*>(&bw[((size_t)(wv) * 64 + lane) * 8]);
        f16x8 wB = *reinterpret_cast<const f16x8*>(&bw[((size_t)(16 + wv) * 64 + lane) * 8]);
        #pragma unroll
        for (int ks = 0; ks < 8; ++ks) {
            f16x8 wN = wB;
            if (ks + 2 < 8)
                wN = *reinterpret_cast<const f16x8*>(
                    &bw[((size_t)((ks + 2) * 16 + wv) * 64 + lane) * 8]);
            #pragma unroll
            for (int et = 0; et < 4; ++et) {
                f16x8 xb = *reinterpret_cast<const f16x8*>(
                    &XF[(ks * 4 + et) * 512 + lane * 8]);
                acc[et] = MFMA16(wA, xb, acc[et]);
            }
            wA = wB; wB = wN;
        }
        __syncthreads();   // all h1 reads done before overwrite
        float4 bs = *reinterpret_cast<const float4*>(&pp[1024 + wv * 16 + g4i * 4]); // eb1
        int ks2 = wv >> 1;
        int lane2 = r16 + 16 * ((wv & 1) * 2 + (g4i >> 1));
        int j0 = (g4i & 1) * 4;
        #pragma unroll
        for (int et = 0; et < 4; ++et) {
            f16x4 hv;
            hv[0] = (f16_t)fmaxf(acc[et][0] + bs.x, 0.f);
            hv[1] = (f16_t)fmaxf(acc[et][1] + bs.y, 0.f);
            hv[2] = (f16_t)fmaxf(acc[et][2] + bs.z, 0.f);
            hv[3] = (f16_t)fmaxf(acc[et][3] + bs.w, 0.f);
            *reinterpret_cast<f16x4*>(&XF[(ks2 * 4 + et) * 512 + lane2 * 8 + j0]) = hv;
        }
    }
    __syncthreads();

    // ---- layer 3 + residual (UN-swapped, prefetch): cols [cw*16,+16)
    {
        const int cw = wv & 7;
        const int rw = wv >> 3;
        f32x4 accF[2] = {}, accR[2] = {};
        const f16_t* bw = pw + 163840;              // ew2 (NT=8)
        f16x8 wA = *reinterpret_cast<const f16x8*>(&bw[((size_t)(cw) * 64 + lane) * 8]);
        f16x8 wB = *reinterpret_cast<const f16x8*>(&bw[((size_t)(8 + cw) * 64 + lane) * 8]);
        #pragma unroll
        for (int ks = 0; ks < 8; ++ks) {
            f16x8 wN = wB;
            if (ks + 2 < 8)
                wN = *reinterpret_cast<const f16x8*>(
                    &bw[((size_t)((ks + 2) * 8 + cw) * 64 + lane) * 8]);
            #pragma unroll
            for (int e2 = 0; e2 < 2; ++e2) {
                f16x8 xa = *reinterpret_cast<const f16x8*>(
                    &XF[(ks * 4 + rw * 2 + e2) * 512 + lane * 8]);
                accF[e2] = MFMA16(xa, wA, accF[e2]);
            }
            wA = wB; wB = wN;
        }
        const f16_t* bwL = pw + 196608;             // eLin (NT=8)
        f16x8 lA = *reinterpret_cast<const f16x8*>(&bwL[((size_t)(cw) * 64 + lane) * 8]);
        f16x8 lB = *reinterpret_cast<const f16x8*>(&bwL[((size_t)(8 + cw) * 64 + lane) * 8]);
        #pragma unroll
        for (int ks = 0; ks < 4; ++ks) {
            f16x8 lN = lB;
            if (ks + 2 < 4)
                lN = *reinterpret_cast<const f16x8*>(
                    &bwL[((size_t)((ks + 2) * 8 + cw) * 64 + lane) * 8]);
            #pragma unroll
            for (int e2 = 0; e2 < 2; ++e2) {
                f16x8 ea = *reinterpret_cast<const f16x8*>(
                    &ERF[(ks * 4 + rw * 2 + e2) * 512 + lane * 8]);
                accR[e2] = MFMA16(ea, lA, accR[e2]);
            }
            lA = lB; lB = lN;
        }
        int c = cw * 16 + r16;
        float bias = pp[1280 + c];                  // eb2
        #pragma unroll
        for (int e2 = 0; e2 < 2; ++e2)
            #pragma unroll
            for (int qi = 0; qi < 4; ++qi) {
                int rr = (rw * 2 + e2) * 16 + g4i * 4 + qi;
                float val = accR[e2][qi] + fmaxf(accF[e2][qi] + bias, 0.f);
                size_t eg2 = ebase + rr;
                __builtin_nontemporal_store(val, &out_e[eg2 * 128 + c]);
                unsafeAtomicAdd(&aggr[(size_t)cidx[rr] * 128 + c], val);
            }
    }
}

// ---------------------------------------------------------------------------
// Node kernel: 32 nodes/block, 512 threads (8 waves). R11 structure,
// pre-rounded params; nt stores for out_v.
// ---------------------------------------------------------------------------
__launch_bounds__(512, 6)
__global__ void node_kernel(
    const float* __restrict__ vfeat, const float* __restrict__ aggr,
    const float* __restrict__ cnts,
    const float* __restrict__ pp,                   // params (node @1408..2559)
    const f16_t* __restrict__ pw,                   // node weight base (nw0)
    float* __restrict__ out_v, int Nn)
{
    __shared__ f16_t X[32 * 264];
    __shared__ f16_t H1[32 * 264];

    const int t    = threadIdx.x;
    const int lane = t & 63;
    const int wv   = t >> 6;           // 0..7
    const size_t nbase = (size_t)blockIdx.x * 32;

    const int nl = t >> 4;
    const int pp16 = t & 15;
    const size_t ng = nbase + nl;
    const bool valid = ng < (size_t)Nn;

    float4 d[4];
    float s = 0.f, sq = 0.f;
    {
        float cmax = 1.f;
        if (valid) cmax = fmaxf(cnts[ng], 1.f);
        const float4* a4 = (const float4*)aggr;
        const float4* v4 = (const float4*)vfeat;
        #pragma unroll
        for (int i = 0; i < 4; ++i) {
            int q = i * 16 + pp16;
            float4 r = make_float4(0.f, 0.f, 0.f, 0.f);
            if (valid) {
                if (q < 32) {
                    r = a4[ng * 32 + q];
                    r.x = r.x / cmax; r.y = r.y / cmax;
                    r.z = r.z / cmax; r.w = r.w / cmax;
                } else {
                    float4 rv = v4[ng * 32 + (q - 32)];
                    r.x = bfr(rv.x); r.y = bfr(rv.y); r.z = bfr(rv.z); r.w = bfr(rv.w);
                }
            }
            d[i] = r;
            s  += r.x + r.y + r.z + r.w;
            sq += r.x*r.x + r.y*r.y + r.z*r.z + r.w*r.w;
        }
    }
    #pragma unroll
    for (int off = 1; off < 16; off <<= 1) {
        s  += __shfl_xor(s, off);
        sq += __shfl_xor(sq, off);
    }
    const float mean = s * (1.f / 256.f);
    const float rstd = 1.f / sqrtf(sq * (1.f / 256.f) - mean * mean + 1e-5f);
    {
        const float4* g4p = (const float4*)(pp + 1408);   // nlng
        const float4* bpp = (const float4*)(pp + 1664);   // nlnb
        #pragma unroll
        for (int i = 0; i < 4; ++i) {
            int q = i * 16 + pp16;
            float4 g = g4p[q]; float4 bb = bpp[q];
            f16x4 y;
            float tt;
            tt = rstd * g.x; y[0] = (f16_t)(d[i].x * tt + (bb.x - mean * tt));
            tt = rstd * g.y; y[1] = (f16_t)(d[i].y * tt + (bb.y - mean * tt));
            tt = rstd * g.z; y[2] = (f16_t)(d[i].z * tt + (bb.z - mean * tt));
            tt = rstd * g.w; y[3] = (f16_t)(d[i].w * tt + (bb.w - mean * tt));
            *reinterpret_cast<f16x4*>(&X[nl * 264 + q * 4]) = y;
        }
    }
    __syncthreads();

    const int r16 = lane & 15;
    const int g4i = lane >> 4;
    const int cb4 = g4i * 4;

    // ---- layer 1 (swapped): wave owns cols [wv*32,+32)
    {
        f32x4 acc[2][2] = {};
        const f16_t* bw = pw;                       // nw0 (NT=16)
        #pragma unroll
        for (int ks = 0; ks < 8; ++ks) {
            f16x8 wa0 = *reinterpret_cast<const f16x8*>(
                &bw[((size_t)(ks * 16 + wv * 2 + 0) * 64 + lane) * 8]);
            f16x8 wa1 = *reinterpret_cast<const f16x8*>(
                &bw[((size_t)(ks * 16 + wv * 2 + 1) * 64 + lane) * 8]);
            #pragma unroll
            for (int nt = 0; nt < 2; ++nt) {
                f16x8 xb = *reinterpret_cast<const f16x8*>(
                    &X[(nt * 16 + r16) * 264 + ks * 32 + g4i * 8]);
                acc[nt][0] = MFMA16(wa0, xb, acc[nt][0]);
                acc[nt][1] = MFMA16(wa1, xb, acc[nt][1]);
            }
        }
        #pragma unroll
        for (int j = 0; j < 2; ++j) {
            int cb = (wv * 2 + j) * 16 + cb4;
            float4 bs = *reinterpret_cast<const float4*>(&pp[1920 + cb]);  // nb0
            #pragma unroll
            for (int nt = 0; nt < 2; ++nt) {
                f16x4 hv;
                hv[0] = (f16_t)fmaxf(acc[nt][j][0] + bs.x, 0.f);
                hv[1] = (f16_t)fmaxf(acc[nt][j][1] + bs.y, 0.f);
                hv[2] = (f16_t)fmaxf(acc[nt][j][2] + bs.z, 0.f);
                hv[3] = (f16_t)fmaxf(acc[nt][j][3] + bs.w, 0.f);
                *reinterpret_cast<f16x4*>(&H1[(nt * 16 + r16) * 264 + cb]) = hv;
            }
        }
    }
    __syncthreads();

    // ---- layer 2 (swapped): into X region
    {
        f32x4 acc[2][2] = {};
        const f16_t* bw = pw + 65536;               // nw1 (NT=16)
        #pragma unroll
        for (int ks = 0; ks < 8; ++ks) {
            f16x8 wa0 = *reinterpret_cast<const f16x8*>(
                &bw[((size_t)(ks * 16 + wv * 2 + 0) * 64 + lane) * 8]);
            f16x8 wa1 = *reinterpret_cast<const f16x8*>(
                &bw[((size_t)(ks * 16 + wv * 2 + 1) * 64 + lane) * 8]);
            #pragma unroll
            for (int nt = 0; nt < 2; ++nt) {
                f16x8 xb = *reinterpret_cast<const f16x8*>(
                    &H1[(nt * 16 + r16) * 264 + ks * 32 + g4i * 8]);
                acc[nt][0] = MFMA16(wa0, xb, acc[nt][0]);
                acc[nt][1] = MFMA16(wa1, xb, acc[nt][1]);
            }
        }
        __syncthreads();
        #pragma unroll
        for (int j = 0; j < 2; ++j) {
            int cb = (wv * 2 + j) * 16 + cb4;
            float4 bs = *reinterpret_cast<const float4*>(&pp[2176 + cb]);  // nb1
            #pragma unroll
            for (int nt = 0; nt < 2; ++nt) {
                f16x4 hv;
                hv[0] = (f16_t)fmaxf(acc[nt][j][0] + bs.x, 0.f);
                hv[1] = (f16_t)fmaxf(acc[nt][j][1] + bs.y, 0.f);
                hv[2] = (f16_t)fmaxf(acc[nt][j][2] + bs.z, 0.f);
                hv[3] = (f16_t)fmaxf(acc[nt][j][3] + bs.w, 0.f);
                *reinterpret_cast<f16x4*>(&X[(nt * 16 + r16) * 264 + cb]) = hv;
            }
        }
    }
    __syncthreads();

    // ---- layer 3 + residual (UN-swapped): wave owns cols [wv*16,+16)
    {
        f32x4 accF[2] = {}, accR[2] = {};
        const f16_t* bw = pw + 131072;              // nw2 (NT=8)
        #pragma unroll
        for (int ks = 0; ks < 8; ++ks) {
            f16x8 wb = *reinterpret_cast<const f16x8*>(
                &bw[((size_t)(ks * 8 + wv) * 64 + lane) * 8]);
            #pragma unroll
            for (int nt = 0; nt < 2; ++nt) {
                f16x8 xa = *reinterpret_cast<const f16x8*>(
                    &X[(nt * 16 + r16) * 264 + ks * 32 + g4i * 8]);
                accF[nt] = MFMA16(xa, wb, accF[nt]);
            }
        }
        const f16_t* bwL = pw + 163840;             // nLin (NT=8)
        #pragma unroll
        for (int ks = 0; ks < 4; ++ks) {
            f16x8 wb = *reinterpret_cast<const f16x8*>(
                &bwL[((size_t)(ks * 8 + wv) * 64 + lane) * 8]);
            #pragma unroll
            for (int nt = 0; nt < 2; ++nt) {
                size_t rv = nbase + (size_t)(nt * 16 + r16);
                if (rv >= (size_t)Nn) rv = (size_t)Nn - 1;
                const float4* src = (const float4*)&vfeat[rv * 128 + ks * 32 + g4i * 8];
                float4 f0 = src[0];
                float4 f1 = src[1];
                f16x8 va;
                va[0] = (f16_t)bfr(f0.x); va[1] = (f16_t)bfr(f0.y);
                va[2] = (f16_t)bfr(f0.z); va[3] = (f16_t)bfr(f0.w);
                va[4] = (f16_t)bfr(f1.x); va[5] = (f16_t)bfr(f1.y);
                va[6] = (f16_t)bfr(f1.z); va[7] = (f16_t)bfr(f1.w);
                accR[nt] = MFMA16(va, wb, accR[nt]);
            }
        }
        int c = wv * 16 + r16;
        float bias = pp[2432 + c];                  // nb2
        #pragma unroll
        for (int nt = 0; nt < 2; ++nt)
            #pragma unroll
            for (int qi = 0; qi < 4; ++qi) {
                int rr = nt * 16 + cb4 + qi;
                size_t ng2 = nbase + rr;
                if (ng2 < (size_t)Nn) {
                    float val = accR[nt][qi] + fmaxf(accF[nt][qi] + bias, 0.f);
                    __builtin_nontemporal_store(val, &out_v[ng2 * 128 + c]);
                }
            }
    }
}

// ---------------------------------------------------------------------------
extern "C" void kernel_launch(void* const* d_in, const int* in_sizes, int n_in,
                              void* d_out, int out_size, void* d_ws, size_t ws_size,
                              hipStream_t stream)
{
    const float* v    = (const float*)d_in[0];
    const float* e    = (const float*)d_in[1];
    const int*   eidx = (const int*)d_in[2];
    const float* elng = (const float*)d_in[3];
    const float* elnb = (const float*)d_in[4];
    const float* ew0  = (const float*)d_in[5];
    const float* eb0  = (const float*)d_in[6];
    const float* ew1  = (const float*)d_in[7];
    const float* eb1  = (const float*)d_in[8];
    const float* ew2  = (const float*)d_in[9];
    const float* eb2  = (const float*)d_in[10];
    const float* eLin = (const float*)d_in[11];
    const float* nlng = (const float*)d_in[12];
    const float* nlnb = (const float*)d_in[13];
    const float* nw0  = (const float*)d_in[14];
    const float* nb0  = (const float*)d_in[15];
    const float* nw1  = (const float*)d_in[16];
    const float* nb1  = (const float*)d_in[17];
    const float* nw2  = (const float*)d_in[18];
    const float* nb2  = (const float*)d_in[19];
    const float* nLin = (const float*)d_in[20];

    const int Nn = in_sizes[0] / 128;
    const int Ee = in_sizes[1] / 128;

    float* out_v = (float*)d_out;
    float* out_e = out_v + (size_t)Nn * 128;

    float* aggr = (float*)d_ws;                       // [Nn][128] f32
    float* cnts = aggr + (size_t)Nn * 128;            // [Nn] f32
    f16_t* packw = (f16_t*)((char*)d_ws + (size_t)Nn * 129 * 4);  // 393216 f16
    float* pp = (float*)((char*)packw + 393216 * 2);  // 2560 f32 params

    hipMemsetAsync(d_ws, 0, (size_t)Nn * 129 * 4, stream);

    pack_weights_kernel<<<192, 256, 0, stream>>>(ew0, ew1, ew2, eLin,
                                                 nw0, nw1, nw2, nLin, packw);
    pack_params_kernel<<<10, 256, 0, stream>>>(elng, elnb, eb0, eb1, eb2,
                                               nlng, nlnb, nb0, nb1, nb2, pp);

    edge_kernel<<<(Ee + 63) / 64, 1024, 0, stream>>>(v, e, eidx, pp, packw,
                                                     out_e, aggr, cnts, Ee);

    node_kernel<<<(Nn + 31) / 32, 512, 0, stream>>>(v, aggr, cnts, pp,
                                                    packw + 212992, out_v, Nn);
}